// Round 3
// baseline (7248.704 us; speedup 1.0000x reference)
//
#include <hip/hip_runtime.h>
#include <cstdint>

#define DEV_INLINE __device__ __forceinline__

constexpr int NB = 32;    // batch
constexpr int NC = 128;   // channels
constexpr int NT = 256;   // seq len
constexpr int ND = 256;   // enc dim
constexpr int NH = 512;   // hidden
constexpr int NSP = 12;
constexpr int NL = NT - NSP;  // 244
constexpr int NNF = 64;
constexpr int NWG = 256;  // recurrence workgroups (1 per CU)

// ---- workspace layout (fp32 words) ----
constexpr size_t ENC_OFF   = 0;                                  // enc[b][t][d]
constexpr size_t ENCT_OFF  = ENC_OFF  + (size_t)NB*NT*ND;        // encT[t][d][b]
constexpr size_t H0_OFF    = ENCT_OFF + (size_t)NT*ND*NB;        // h0 slabs t=-1..255 -> 257 x [k][b]
constexpr size_t H1_OFF    = H0_OFF   + (size_t)(NT+1)*NH*NB;
constexpr size_t CTX_OFF   = H1_OFF   + (size_t)(NT+1)*NH*NB;    // ctx[l][b][d]
constexpr size_t CE_OFF    = CTX_OFF  + (size_t)NL*NB*ND;        // ce[l*32+b]
constexpr size_t FLAGS_OFF = CE_OFF   + (size_t)NL*NB;           // 256 uint flags

// K3 dynamic LDS: A region (max 1024*36+128 words) + redbuf (2304) + cstate (128)
constexpr int K3_SMEM_BYTES = (1024*36 + 128 + 2304 + 128) * 4;  // 157,696 B

DEV_INLINE float sigm(float x) { return 1.0f / (1.0f + expf(-x)); }

// ---------------- K1: encoder GEMM + zero-init of flags / h[-1] slabs ----------------
// grid 128 = (b, t-tile of 64), 256 threads
__global__ __launch_bounds__(256) void k1_encoder(float* __restrict__ ws,
                                                  const float* __restrict__ x,
                                                  const float* __restrict__ W_enc,
                                                  const float* __restrict__ b_enc) {
  const int blk = blockIdx.x, tid = threadIdx.x;
  // zero duty: flags (block 0) + h0/h1 slab -1 (128 floats each per block)
  if (blk == 0) ((unsigned int*)(ws + FLAGS_OFF))[tid] = 0u;
  if (tid < 128) ws[H0_OFF + (size_t)blk*128 + tid] = 0.0f;
  else           ws[H1_OFF + (size_t)blk*128 + (tid-128)] = 0.0f;

  const int b = blk >> 2;
  const int t0 = (blk & 3) * 64;
  __shared__ float xs[NC][64];
  const int lane = tid & 63, wq = tid >> 6;
  for (int c = wq; c < NC; c += 4)
    xs[c][lane] = x[((size_t)(b*NC + c))*NT + t0 + lane];   // coalesced along t
  __syncthreads();

  const int d = tid;
  const float be = b_enc[d];
  float4 acc[16];
#pragma unroll
  for (int q = 0; q < 16; ++q) { acc[q].x = be; acc[q].y = be; acc[q].z = be; acc[q].w = be; }
  for (int c = 0; c < NC; ++c) {
    const float w = W_enc[(size_t)c*ND + d];     // coalesced, L2-hot
    const float4* xr = (const float4*)(&xs[c][0]);
#pragma unroll
    for (int q = 0; q < 16; ++q) {
      float4 xv = xr[q];
      acc[q].x += xv.x*w; acc[q].y += xv.y*w; acc[q].z += xv.z*w; acc[q].w += xv.w*w;
    }
  }
#pragma unroll
  for (int q = 0; q < 16; ++q) {
    ws[ENC_OFF + ((size_t)(b*NT + t0 + q*4 + 0))*ND + d] = acc[q].x;
    ws[ENC_OFF + ((size_t)(b*NT + t0 + q*4 + 1))*ND + d] = acc[q].y;
    ws[ENC_OFF + ((size_t)(b*NT + t0 + q*4 + 2))*ND + d] = acc[q].z;
    ws[ENC_OFF + ((size_t)(b*NT + t0 + q*4 + 3))*ND + d] = acc[q].w;
  }
}

// ---------------- K2: transpose enc[b][t][d] -> encT[t][d][b] ----------------
// grid 1024 = (t, d-quad of 64), 256 threads
__global__ __launch_bounds__(256) void k2_transpose(float* __restrict__ ws) {
  const int t = blockIdx.x >> 2;
  const int d0 = (blockIdx.x & 3) * 64;
  const int tid = threadIdx.x;
  __shared__ float tile[NB][65];  // +1 pad: write-phase reads stride-65 -> conflict-free
  const int lane = tid & 63, wq = tid >> 6;
  for (int b = wq; b < NB; b += 4)
    tile[b][lane] = ws[ENC_OFF + ((size_t)(b*NT + t))*ND + d0 + lane];  // coalesced
  __syncthreads();
#pragma unroll
  for (int i = 0; i < 8; ++i) {
    int idx = i*256 + tid;
    int dd = idx >> 5, b = idx & 31;
    ws[ENCT_OFF + ((size_t)(t*ND + d0 + dd))*NB + b] = tile[b][dd];     // coalesced
  }
}

// ---------------- grid barrier (monotonic flags, agent-scope) ----------------
// NPOLL: how many leading flags to wait on (L0 wgs depend only on L0 flags).
template<int NPOLL>
DEV_INLINE void grid_barrier(unsigned int* flags, int wg, unsigned int target, int tid) {
  __syncthreads();  // all threads' h-stores drained (vmcnt0 before s_barrier)
  if (tid == 0)
    __hip_atomic_store(&flags[wg], target, __ATOMIC_RELEASE, __HIP_MEMORY_SCOPE_AGENT);
  if (tid < 64) {
    for (;;) {
      bool ok = true;
#pragma unroll
      for (int i = 0; i < NPOLL/64; ++i) {
        unsigned int v = __hip_atomic_load(&flags[tid + i*64], __ATOMIC_RELAXED, __HIP_MEMORY_SCOPE_AGENT);
        ok = ok && (v >= target);
      }
      if (__all(ok)) break;
      __builtin_amdgcn_s_sleep(1);
    }
  }
  __syncthreads();
  __builtin_amdgcn_fence(__ATOMIC_ACQUIRE, "agent");  // invalidate stale L2 before plain loads
}

// ---------------- K3: persistent pipelined 2-layer LSTM recurrence ----------------
// 256 wgs x 256 threads, 1 wg/CU (LDS-capped -> full 512-VGPR/wave budget).
// wg<128: layer0, else layer1. Per wg: 16 gate-rows (4 units x 4 gates), weights in
// VGPRs (2 rows x KC per thread), A=[k][b] staged in LDS with per-chunk +4-word pad
// (8 ks-groups/wave -> 8 distinct bank-quads -> conflict-free broadcast b128 reads).
template<int KC, int WBS, int LAYER>
DEV_INLINE void lstm_loop(float* __restrict__ ws, float* __restrict__ smem,
                          const float* __restrict__ Wa, const float* __restrict__ Wb,
                          const float* __restrict__ bih, const float* __restrict__ bhh,
                          int u0, int tid, int wg) {
  constexpr int KTOT = KC * 32;            // 768 (L0) or 1024 (L1)
  constexpr int NI   = KTOT / 256;         // staged rows per thread (3 or 4)
  constexpr int AW   = KTOT*36 + 128;      // A region words
  constexpr int NPOLL = (LAYER == 0) ? 128 : 256;
  float* redbuf = smem + AW;               // [4][16][36]
  float* cst    = redbuf + 2304;           // c-state [128]
  unsigned int* flags = (unsigned int*)(ws + FLAGS_OFF);

  const int rg = tid & 7, ks = tid >> 3;

  // --- persistent weight registers: 2 rows x KC (float4 preload) ---
  int row[2];
#pragma unroll
  for (int j = 0; j < 2; ++j) {
    int ridx = rg*2 + j;                   // gate = ridx&3, unit-lane = ridx>>2
    row[j] = (ridx & 3)*NH + u0 + (ridx >> 2);
  }
  float wreg[2][KC];
#pragma unroll
  for (int k0 = 0; k0 < KC/4; ++k0) {
    const int kk = ks*KC + k0*4;           // 16B-aligned; NH boundary is float4-aligned
#pragma unroll
    for (int j = 0; j < 2; ++j) {
      const float4 w4 = (kk < NH)
        ? *(const float4*)&Wa[(size_t)row[j]*NH + kk]
        : *(const float4*)&Wb[(size_t)row[j]*WBS + (kk - NH)];
      wreg[j][k0*4+0] = w4.x; wreg[j][k0*4+1] = w4.y;
      wreg[j][k0*4+2] = w4.z; wreg[j][k0*4+3] = w4.w;
    }
  }
  // --- finalize-thread constants + c-state init ---
  float bsum[4] = {0,0,0,0};
  if (tid < 128) {
    int ul = tid >> 5;
#pragma unroll
    for (int g = 0; g < 4; ++g)
      bsum[g] = bih[g*NH + u0 + ul] + bhh[g*NH + u0 + ul];
    cst[tid] = 0.0f;
  }
  __syncthreads();

  const float* Aread = smem + (size_t)ks * (KC*36 + 4);

  for (int s = 0; s <= NT; ++s) {
    const int t = (LAYER == 0) ? s : s - 1;
    const bool active = (LAYER == 0) ? (s < NT) : (s >= 1);
    if (active) {
      const float* srcA = (LAYER == 0) ? ws + H0_OFF + (size_t)t*NH*NB        // h0[t-1]
                                       : ws + H0_OFF + (size_t)(t+1)*NH*NB;   // h0[t]
      const float* srcB = (LAYER == 0) ? ws + ENCT_OFF + (size_t)t*ND*NB      // enc_t[d][b]
                                       : ws + H1_OFF + (size_t)t*NH*NB;       // h1[t-1]
      float* hout = ((LAYER == 0) ? ws + H0_OFF : ws + H1_OFF) + (size_t)(t+1)*NH*NB;

      // --- stage A into LDS: issue ALL global loads first (MLP), then write.
      //     row k = i*256+tid, word addr k*36 + (k/KC)*4 ---
      {
        float4 v[NI][8];
#pragma unroll
        for (int i = 0; i < NI; ++i) {
          const int k = i*256 + tid;
          const float* src = (i < 2) ? srcA + (size_t)k*NB : srcB + (size_t)(k - NH)*NB;
#pragma unroll
          for (int m = 0; m < 8; ++m) v[i][m] = ((const float4*)src)[m];
        }
#pragma unroll
        for (int i = 0; i < NI; ++i) {
          const int k = i*256 + tid;
          float* dst = smem + (size_t)k*36 + (k/KC)*4;
#pragma unroll
          for (int m = 0; m < 8; ++m) ((float4*)dst)[m] = v[i][m];
        }
      }
      __syncthreads();

      // --- FMA: partial dots over this thread's K-chunk, 2 rows x 32 batches ---
      float4 acc[2][8];
#pragma unroll
      for (int j = 0; j < 2; ++j)
#pragma unroll
        for (int m = 0; m < 8; ++m) { acc[j][m].x = 0; acc[j][m].y = 0; acc[j][m].z = 0; acc[j][m].w = 0; }
#pragma unroll
      for (int k = 0; k < KC; ++k) {
        const float4* ar = (const float4*)(Aread + (size_t)k*36);
        const float w0 = wreg[0][k], w1 = wreg[1][k];
#pragma unroll
        for (int m = 0; m < 8; ++m) {
          float4 a = ar[m];
          acc[0][m].x += a.x*w0; acc[0][m].y += a.y*w0; acc[0][m].z += a.z*w0; acc[0][m].w += a.w*w0;
          acc[1][m].x += a.x*w1; acc[1][m].y += a.y*w1; acc[1][m].z += a.z*w1; acc[1][m].w += a.w*w1;
        }
      }

      // --- intra-wave reduce over ks (tid bits 3..5) ---
#pragma unroll
      for (int mask = 8; mask <= 32; mask <<= 1) {
#pragma unroll
        for (int j = 0; j < 2; ++j)
#pragma unroll
          for (int m = 0; m < 8; ++m) {
            acc[j][m].x += __shfl_xor(acc[j][m].x, mask, 64);
            acc[j][m].y += __shfl_xor(acc[j][m].y, mask, 64);
            acc[j][m].z += __shfl_xor(acc[j][m].z, mask, 64);
            acc[j][m].w += __shfl_xor(acc[j][m].w, mask, 64);
          }
      }
      if ((tid & 56) == 0) {          // one lane-group per wave writes wave-partials
        int wv = tid >> 6;
#pragma unroll
        for (int j = 0; j < 2; ++j)
#pragma unroll
          for (int m = 0; m < 8; ++m)
            *((float4*)(redbuf + (size_t)(wv*16 + rg*2 + j)*36 + 4*m)) = acc[j][m];
      }
      __syncthreads();

      // --- finalize: sum 4 wave-partials + bias, LSTM cell update, write h ---
      if (tid < 128) {
        int ul = tid >> 5, b = tid & 31;
        float gv[4];
#pragma unroll
        for (int g = 0; g < 4; ++g) {
          float ssum = bsum[g];
#pragma unroll
          for (int wv = 0; wv < 4; ++wv)
            ssum += redbuf[(size_t)(wv*16 + ul*4 + g)*36 + b];
          gv[g] = ssum;
        }
        float ig = sigm(gv[0]);
        float fg = sigm(gv[1]);
        float gg = tanhf(gv[2]);
        float og = sigm(gv[3]);
        float c = fg * cst[tid] + ig * gg;
        cst[tid] = c;
        hout[(size_t)(u0 + ul)*NB + b] = og * tanhf(c);
      }
    }
    if (s < NT) grid_barrier<NPOLL>(flags, wg, (unsigned int)(s + 1), tid);
  }
}

__global__ __launch_bounds__(256, 1) void k3_recurrence(float* ws,
    const float* Whh0, const float* Wih0, const float* bih0, const float* bhh0,
    const float* Wih1, const float* Whh1, const float* bih1, const float* bhh1) {
  extern __shared__ float smem[];
  const int wg = blockIdx.x, tid = threadIdx.x;
  if (wg < 128) lstm_loop<24, 256, 0>(ws, smem, Whh0, Wih0, bih0, bhh0, (wg)*4, tid, wg);
  else          lstm_loop<32, 512, 1>(ws, smem, Wih1, Whh1, bih1, bhh1, (wg-128)*4, tid, wg);
}

// ---------------- K4: ctx[l][b][d] = h1[t] @ Wp + bp ----------------
// grid 244 (= t), 256 threads (= d); h1[t] tile staged in LDS
__global__ __launch_bounds__(256) void k4_proj(float* __restrict__ ws,
                                               const float* __restrict__ Wp,
                                               const float* __restrict__ bp) {
  const int t = blockIdx.x, tid = threadIdx.x;
  extern __shared__ float sh[];  // h1[t][k][b]: 512*32 floats
  const float* hsrc = ws + H1_OFF + (size_t)(t+1)*NH*NB;
  for (int i = 0; i < 64; ++i) sh[i*256 + tid] = hsrc[i*256 + tid];  // coalesced
  __syncthreads();
  const int d = tid;
  const float bpd = bp[d];
  float4 acc[8];
#pragma unroll
  for (int q = 0; q < 8; ++q) { acc[q].x = bpd; acc[q].y = bpd; acc[q].z = bpd; acc[q].w = bpd; }
  for (int k = 0; k < NH; ++k) {
    const float w = Wp[(size_t)k*ND + d];       // coalesced
    const float4* hr = (const float4*)(sh + (size_t)k*NB);
#pragma unroll
    for (int q = 0; q < 8; ++q) {
      float4 h = hr[q];                          // broadcast read
      acc[q].x += h.x*w; acc[q].y += h.y*w; acc[q].z += h.z*w; acc[q].w += h.w*w;
    }
  }
#pragma unroll
  for (int q = 0; q < 8; ++q) {
    ws[CTX_OFF + ((size_t)t*NB + q*4 + 0)*ND + d] = acc[q].x;
    ws[CTX_OFF + ((size_t)t*NB + q*4 + 1)*ND + d] = acc[q].y;
    ws[CTX_OFF + ((size_t)t*NB + q*4 + 2)*ND + d] = acc[q].z;
    ws[CTX_OFF + ((size_t)t*NB + q*4 + 3)*ND + d] = acc[q].w;
  }
}

// ---------------- K5: 65 dot-products + logsumexp -> ce[l,b] ----------------
// grid 7808 = (l,b), 256 threads = 4 waves; each wave handles preds n = wv, wv+4, ...
__global__ __launch_bounds__(256) void k5_scores(float* __restrict__ ws,
                                                 const int* __restrict__ idxs) {
  const int blk = blockIdx.x;
  const int l = blk >> 5, b = blk & 31;
  const int tid = threadIdx.x, lane = tid & 63, wv = tid >> 6;
  const float* ctx = ws + CTX_OFF + ((size_t)l*NB + b)*ND;
  const float4 c4 = ((const float4*)ctx)[lane];
  __shared__ float preds[66];
  for (int n = wv; n < 65; n += 4) {
    const float* rowp;
    if (n == 0) {
      rowp = ws + ENC_OFF + ((size_t)(b*NT + NSP + l))*ND;
    } else {
      int idx = idxs[(size_t)l*(NB*NNF) + b*NNF + (n-1)];
      int sq = idx % (NT-1);
      int bb = idx / (NT-1);
      sq += (sq >= l + NSP) ? 1 : 0;
      rowp = ws + ENC_OFF + ((size_t)(bb*NT + sq))*ND;
    }
    float4 r4 = ((const float4*)rowp)[lane];
    float p = c4.x*r4.x + c4.y*r4.y + c4.z*r4.z + c4.w*r4.w;
#pragma unroll
    for (int m = 1; m < 64; m <<= 1) p += __shfl_xor(p, m, 64);
    if (lane == 0) preds[n] = p;
  }
  __syncthreads();
  if (wv == 0) {
    float p = preds[lane];
    float p64 = preds[64], p0 = preds[0];
    float mx = p;
#pragma unroll
    for (int m = 1; m < 64; m <<= 1) mx = fmaxf(mx, __shfl_xor(mx, m, 64));
    mx = fmaxf(mx, p64);
    float e = expf(p - mx);
#pragma unroll
    for (int m = 1; m < 64; m <<= 1) e += __shfl_xor(e, m, 64);
    e += expf(p64 - mx);
    if (lane == 0) ws[CE_OFF + (size_t)l*NB + b] = mx + logf(e) - p0;
  }
}

// ---------------- K6: loss = sum(ce) / 32 ----------------
__global__ __launch_bounds__(256) void k6_reduce(const float* __restrict__ ws,
                                                 float* __restrict__ out) {
  const int tid = threadIdx.x;
  float s = 0.0f;
  for (int i = tid; i < NL*NB; i += 256) s += ws[CE_OFF + i];
  __shared__ float red[256];
  red[tid] = s;
  __syncthreads();
  for (int off = 128; off > 0; off >>= 1) {
    if (tid < off) red[tid] += red[tid + off];
    __syncthreads();
  }
  if (tid == 0) out[0] = red[0] * (1.0f / 32.0f);
}

// ---------------- launcher ----------------
extern "C" void kernel_launch(void* const* d_in, const int* in_sizes, int n_in,
                              void* d_out, int out_size, void* d_ws, size_t ws_size,
                              hipStream_t stream) {
  const float* x     = (const float*)d_in[0];
  const float* W_enc = (const float*)d_in[1];
  const float* b_enc = (const float*)d_in[2];
  const float* Wih0  = (const float*)d_in[3];
  const float* Whh0  = (const float*)d_in[4];
  const float* bih0  = (const float*)d_in[5];
  const float* bhh0  = (const float*)d_in[6];
  const float* Wih1  = (const float*)d_in[7];
  const float* Whh1  = (const float*)d_in[8];
  const float* bih1  = (const float*)d_in[9];
  const float* bhh1  = (const float*)d_in[10];
  const float* Wp    = (const float*)d_in[11];
  const float* bp    = (const float*)d_in[12];
  const int*   idxs  = (const int*)d_in[13];
  float* ws  = (float*)d_ws;
  float* out = (float*)d_out;

  (void)in_sizes; (void)n_in; (void)out_size; (void)ws_size;

  hipFuncSetAttribute((const void*)k3_recurrence,
                      hipFuncAttributeMaxDynamicSharedMemorySize, K3_SMEM_BYTES);
  hipFuncSetAttribute((const void*)k4_proj,
                      hipFuncAttributeMaxDynamicSharedMemorySize, 65536);

  k1_encoder  <<<128,  256, 0, stream>>>(ws, x, W_enc, b_enc);
  k2_transpose<<<1024, 256, 0, stream>>>(ws);

  // K3: cooperative launch guarantees co-residency of all 256 wgs (1/CU).
  // Fallback to a plain launch if cooperative isn't available; at 1 wg/CU with
  // an otherwise-idle exclusive GPU the dispatcher fills all 256 CUs.
  {
    float* ws_ = ws;
    const float *a0 = Whh0, *a1 = Wih0, *a2 = bih0, *a3 = bhh0;
    const float *a4 = Wih1, *a5 = Whh1, *a6 = bih1, *a7 = bhh1;
    void* params[] = {(void*)&ws_, (void*)&a0, (void*)&a1, (void*)&a2, (void*)&a3,
                      (void*)&a4, (void*)&a5, (void*)&a6, (void*)&a7};
    hipError_t err = hipLaunchCooperativeKernel((const void*)k3_recurrence,
                                                dim3(NWG), dim3(256), params,
                                                K3_SMEM_BYTES, stream);
    if (err != hipSuccess) {
      k3_recurrence<<<NWG, 256, K3_SMEM_BYTES, stream>>>(ws, Whh0, Wih0, bih0, bhh0,
                                                         Wih1, Whh1, bih1, bhh1);
    }
  }

  k4_proj     <<<NL,   256, 65536, stream>>>(ws, Wp, bp);
  k5_scores   <<<NL*NB,256, 0, stream>>>(ws, idxs);
  k6_reduce   <<<1,    256, 0, stream>>>(ws, out);
}

// Round 5
// 6357.419 us; speedup vs baseline: 1.1402x; 1.1402x over previous
//
#include <hip/hip_runtime.h>
#include <cstdint>

#define DEV_INLINE __device__ __forceinline__

typedef float  f32x4 __attribute__((ext_vector_type(4)));
typedef double f64x2 __attribute__((ext_vector_type(2)));

constexpr int NB = 32;    // batch
constexpr int NC = 128;   // channels
constexpr int NT = 256;   // seq len
constexpr int ND = 256;   // enc dim
constexpr int NH = 512;   // hidden
constexpr int NSP = 12;
constexpr int NL = NT - NSP;  // 244
constexpr int NNF = 64;
constexpr int NWG = 256;  // recurrence workgroups (1 per CU)

// ---- workspace layout (fp32 words) ----
constexpr size_t ENC_OFF   = 0;                                  // enc[b][t][d]
constexpr size_t ENCT_OFF  = ENC_OFF  + (size_t)NB*NT*ND;        // encT[t][d][b]
constexpr size_t H0_OFF    = ENCT_OFF + (size_t)NT*ND*NB;        // h0 slabs t=-1..255 -> 257 x [k][b]
constexpr size_t H1_OFF    = H0_OFF   + (size_t)(NT+1)*NH*NB;
constexpr size_t CTX_OFF   = H1_OFF   + (size_t)(NT+1)*NH*NB;    // ctx[l][b][d]
constexpr size_t CE_OFF    = CTX_OFF  + (size_t)NL*NB*ND;        // ce[l*32+b]
constexpr size_t FLAGS_OFF = CE_OFF   + (size_t)NL*NB;           // 256 uint flags

// K3 dynamic LDS: A region (max 1024*36+128 words) + redbuf (2304) + cstate (128)
constexpr int K3_SMEM_BYTES = (1024*36 + 128 + 2304 + 128) * 4;  // 157,696 B

DEV_INLINE float sigm(float x) { return 1.0f / (1.0f + expf(-x)); }

// ---------------- K1: encoder GEMM + zero-init of flags / h[-1] slabs ----------------
// grid 128 = (b, t-tile of 64), 256 threads
__global__ __launch_bounds__(256) void k1_encoder(float* __restrict__ ws,
                                                  const float* __restrict__ x,
                                                  const float* __restrict__ W_enc,
                                                  const float* __restrict__ b_enc) {
  const int blk = blockIdx.x, tid = threadIdx.x;
  // zero duty: flags (block 0) + h0/h1 slab -1 (128 floats each per block)
  if (blk == 0) ((unsigned int*)(ws + FLAGS_OFF))[tid] = 0u;
  if (tid < 128) ws[H0_OFF + (size_t)blk*128 + tid] = 0.0f;
  else           ws[H1_OFF + (size_t)blk*128 + (tid-128)] = 0.0f;

  const int b = blk >> 2;
  const int t0 = (blk & 3) * 64;
  __shared__ float xs[NC][64];
  const int lane = tid & 63, wq = tid >> 6;
  for (int c = wq; c < NC; c += 4)
    xs[c][lane] = x[((size_t)(b*NC + c))*NT + t0 + lane];   // coalesced along t
  __syncthreads();

  const int d = tid;
  const float be = b_enc[d];
  float4 acc[16];
#pragma unroll
  for (int q = 0; q < 16; ++q) { acc[q].x = be; acc[q].y = be; acc[q].z = be; acc[q].w = be; }
  for (int c = 0; c < NC; ++c) {
    const float w = W_enc[(size_t)c*ND + d];     // coalesced, L2-hot
    const float4* xr = (const float4*)(&xs[c][0]);
#pragma unroll
    for (int q = 0; q < 16; ++q) {
      float4 xv = xr[q];
      acc[q].x += xv.x*w; acc[q].y += xv.y*w; acc[q].z += xv.z*w; acc[q].w += xv.w*w;
    }
  }
#pragma unroll
  for (int q = 0; q < 16; ++q) {
    ws[ENC_OFF + ((size_t)(b*NT + t0 + q*4 + 0))*ND + d] = acc[q].x;
    ws[ENC_OFF + ((size_t)(b*NT + t0 + q*4 + 1))*ND + d] = acc[q].y;
    ws[ENC_OFF + ((size_t)(b*NT + t0 + q*4 + 2))*ND + d] = acc[q].z;
    ws[ENC_OFF + ((size_t)(b*NT + t0 + q*4 + 3))*ND + d] = acc[q].w;
  }
}

// ---------------- K2: transpose enc[b][t][d] -> encT[t][d][b] ----------------
// grid 1024 = (t, d-quad of 64), 256 threads
__global__ __launch_bounds__(256) void k2_transpose(float* __restrict__ ws) {
  const int t = blockIdx.x >> 2;
  const int d0 = (blockIdx.x & 3) * 64;
  const int tid = threadIdx.x;
  __shared__ float tile[NB][65];  // +1 pad: write-phase reads stride-65 -> conflict-free
  const int lane = tid & 63, wq = tid >> 6;
  for (int b = wq; b < NB; b += 4)
    tile[b][lane] = ws[ENC_OFF + ((size_t)(b*NT + t))*ND + d0 + lane];  // coalesced
  __syncthreads();
#pragma unroll
  for (int i = 0; i < 8; ++i) {
    int idx = i*256 + tid;
    int dd = idx >> 5, b = idx & 31;
    ws[ENCT_OFF + ((size_t)(t*ND + d0 + dd))*NB + b] = tile[b][dd];     // coalesced
  }
}

// ---------------- grid barrier: write-through flags, NO L2 maintenance ----------------
// Protocol: producers store h via agent-scope relaxed atomics (write-through, never
// dirty in L2); __syncthreads drains vmcnt -> stores at coherence point; flag store
// agent-relaxed; consumers poll agent-relaxed and read h via agent-relaxed atomic
// loads (L2-bypass, fetch fresh). No buffer_wbl2 / buffer_inv anywhere.
// Timeout: if a flag never arrives (~131K polls), give up permanently -> kernel
// terminates with wrong results (diagnosable) instead of wedging the GPU.
template<int NPOLL>
DEV_INLINE void grid_barrier(unsigned int* flags, int wg, unsigned int target, int tid,
                             bool& gaveup) {
  __syncthreads();  // vmcnt(0): this wg's write-through h-stores have reached LLC
  if (tid == 0)
    __hip_atomic_store(&flags[wg], target, __ATOMIC_RELAXED, __HIP_MEMORY_SCOPE_AGENT);
  if (tid < 64 && !gaveup) {
    int iters = 0;
    for (;;) {
      bool ok = true;
#pragma unroll
      for (int i = 0; i < NPOLL/64; ++i) {
        unsigned int v = __hip_atomic_load(&flags[tid + i*64], __ATOMIC_RELAXED, __HIP_MEMORY_SCOPE_AGENT);
        ok = ok && (v >= target);
      }
      if (__all(ok)) break;
      if (++iters > (1 << 17)) { gaveup = true; break; }
      __builtin_amdgcn_s_sleep(2);
    }
  }
  __syncthreads();
}

// ---------------- K3: persistent pipelined 2-layer LSTM recurrence ----------------
// 256 wgs x 256 threads, 1 wg/CU (LDS-capped -> 1 wave/SIMD, full 512-VGPR budget).
// wg<128: layer0, else layer1. Per wg: 16 gate-rows (4 units x 4 gates), weights in
// VGPRs (2 rows x KC per thread), A=[k][b] staged in LDS with per-chunk +4-word pad
// (8 ks-groups/wave -> 8 distinct bank-quads -> conflict-free broadcast b128 reads).
template<int KC, int WBS, int LAYER>
DEV_INLINE void lstm_loop(float* __restrict__ ws, float* __restrict__ smem,
                          const float* __restrict__ Wa, const float* __restrict__ Wb,
                          const float* __restrict__ bih, const float* __restrict__ bhh,
                          int u0, int tid, int wg) {
  constexpr int KTOT = KC * 32;            // 768 (L0) or 1024 (L1)
  constexpr int NHROWS = (LAYER == 0) ? 2 : 4;  // h-slab rows staged per thread
  constexpr int AW   = KTOT*36 + 128;      // A region words
  constexpr int NPOLL = (LAYER == 0) ? 128 : 256;
  float* redbuf = smem + AW;               // [4][16][36]
  float* cst    = redbuf + 2304;           // c-state [128]
  unsigned int* flags = (unsigned int*)(ws + FLAGS_OFF);

  const int rg = tid & 7, ks = tid >> 3;
  bool gaveup = false;

  // --- persistent weight registers: 2 rows x KC (float4 preload) ---
  int row[2];
#pragma unroll
  for (int j = 0; j < 2; ++j) {
    int ridx = rg*2 + j;                   // gate = ridx&3, unit-lane = ridx>>2
    row[j] = (ridx & 3)*NH + u0 + (ridx >> 2);
  }
  float wreg[2][KC];
#pragma unroll
  for (int k0 = 0; k0 < KC/4; ++k0) {
    const int kk = ks*KC + k0*4;           // 16B-aligned; NH boundary is float4-aligned
#pragma unroll
    for (int j = 0; j < 2; ++j) {
      const float4 w4 = (kk < NH)
        ? *(const float4*)&Wa[(size_t)row[j]*NH + kk]
        : *(const float4*)&Wb[(size_t)row[j]*WBS + (kk - NH)];
      wreg[j][k0*4+0] = w4.x; wreg[j][k0*4+1] = w4.y;
      wreg[j][k0*4+2] = w4.z; wreg[j][k0*4+3] = w4.w;
    }
  }
  // --- finalize-thread constants + c-state init ---
  float bsum[4] = {0,0,0,0};
  if (tid < 128) {
    int ul = tid >> 5;
#pragma unroll
    for (int g = 0; g < 4; ++g)
      bsum[g] = bih[g*NH + u0 + ul] + bhh[g*NH + u0 + ul];
    cst[tid] = 0.0f;
  }
  __syncthreads();

  const float* Aread = smem + (size_t)ks * (KC*36 + 4);

  for (int s = 0; s <= NT; ++s) {
    const int t = (LAYER == 0) ? s : s - 1;
    const bool active = (LAYER == 0) ? (s < NT) : (s >= 1);
    if (active) {
      const float* srcA = (LAYER == 0) ? ws + H0_OFF + (size_t)t*NH*NB        // h0[t-1]
                                       : ws + H0_OFF + (size_t)(t+1)*NH*NB;   // h0[t]
      const float* srcB = (LAYER == 0) ? ws + ENCT_OFF + (size_t)t*ND*NB      // enc_t[d][b]
                                       : ws + H1_OFF + (size_t)t*NH*NB;       // h1[t-1]
      float* hout = ((LAYER == 0) ? ws + H0_OFF : ws + H1_OFF) + (size_t)(t+1)*NH*NB;

      // --- stage A into LDS. h-slab rows: agent-scope atomic 8B loads (correct
      //     coherence bits, compiler-managed waits). encT row (L0): plain cached.
      //     All loads issued before all LDS writes (sched_barrier fence).
      //     row k = i*256+tid, word addr k*36 + (k/KC)*4 ---
      {
        double vh[NHROWS][16];
        f32x4 ve[8];
#pragma unroll
        for (int i = 0; i < NHROWS; ++i) {
          const int k = i*256 + tid;
          const double* src = (i < 2) ? (const double*)(srcA + (size_t)k*NB)
                                      : (const double*)(srcB + (size_t)(k - NH)*NB);
#pragma unroll
          for (int m = 0; m < 16; ++m)
            vh[i][m] = __hip_atomic_load(src + m, __ATOMIC_RELAXED, __HIP_MEMORY_SCOPE_AGENT);
        }
        if (LAYER == 0) {
          const float* src = srcB + (size_t)tid*NB;   // encT row k=512+tid -> k-NH=tid
#pragma unroll
          for (int m = 0; m < 8; ++m) ve[m] = ((const f32x4*)src)[m];
        }
        __builtin_amdgcn_sched_barrier(0);   // keep all issues above all LDS writes
#pragma unroll
        for (int i = 0; i < NHROWS; ++i) {
          const int k = i*256 + tid;
          float* dst = smem + (size_t)k*36 + (k/KC)*4;
#pragma unroll
          for (int m = 0; m < 8; ++m) {
            f64x2 p; p.x = vh[i][2*m]; p.y = vh[i][2*m+1];
            ((f64x2*)dst)[m] = p;                      // ds_write_b128
          }
        }
        if (LAYER == 0) {
          const int k = 512 + tid;
          float* dst = smem + (size_t)k*36 + (k/KC)*4;
#pragma unroll
          for (int m = 0; m < 8; ++m) ((f32x4*)dst)[m] = ve[m];
        }
      }
      __syncthreads();

      // --- FMA: partial dots over this thread's K-chunk, 2 rows x 32 batches ---
      float4 acc[2][8];
#pragma unroll
      for (int j = 0; j < 2; ++j)
#pragma unroll
        for (int m = 0; m < 8; ++m) { acc[j][m].x = 0; acc[j][m].y = 0; acc[j][m].z = 0; acc[j][m].w = 0; }
#pragma unroll
      for (int k = 0; k < KC; ++k) {
        const float4* ar = (const float4*)(Aread + (size_t)k*36);
        const float w0 = wreg[0][k], w1 = wreg[1][k];
#pragma unroll
        for (int m = 0; m < 8; ++m) {
          float4 a = ar[m];
          acc[0][m].x += a.x*w0; acc[0][m].y += a.y*w0; acc[0][m].z += a.z*w0; acc[0][m].w += a.w*w0;
          acc[1][m].x += a.x*w1; acc[1][m].y += a.y*w1; acc[1][m].z += a.z*w1; acc[1][m].w += a.w*w1;
        }
      }

      // --- intra-wave reduce over ks (tid bits 3..5) ---
#pragma unroll
      for (int mask = 8; mask <= 32; mask <<= 1) {
#pragma unroll
        for (int j = 0; j < 2; ++j)
#pragma unroll
          for (int m = 0; m < 8; ++m) {
            acc[j][m].x += __shfl_xor(acc[j][m].x, mask, 64);
            acc[j][m].y += __shfl_xor(acc[j][m].y, mask, 64);
            acc[j][m].z += __shfl_xor(acc[j][m].z, mask, 64);
            acc[j][m].w += __shfl_xor(acc[j][m].w, mask, 64);
          }
      }
      if ((tid & 56) == 0) {          // one lane-group per wave writes wave-partials
        int wv = tid >> 6;
#pragma unroll
        for (int j = 0; j < 2; ++j)
#pragma unroll
          for (int m = 0; m < 8; ++m)
            *((float4*)(redbuf + (size_t)(wv*16 + rg*2 + j)*36 + 4*m)) = acc[j][m];
      }
      __syncthreads();

      // --- finalize: sum 4 wave-partials + bias, LSTM cell update, write h ---
      if (tid < 128) {
        int ul = tid >> 5, b = tid & 31;
        float gv[4];
#pragma unroll
        for (int g = 0; g < 4; ++g) {
          float ssum = bsum[g];
#pragma unroll
          for (int wv = 0; wv < 4; ++wv)
            ssum += redbuf[(size_t)(wv*16 + ul*4 + g)*36 + b];
          gv[g] = ssum;
        }
        float ig = sigm(gv[0]);
        float fg = sigm(gv[1]);
        float gg = tanhf(gv[2]);
        float og = sigm(gv[3]);
        float c = fg * cst[tid] + ig * gg;
        cst[tid] = c;
        // write-through store: never dirty in L2, at LLC after vmcnt drain
        __hip_atomic_store(&hout[(size_t)(u0 + ul)*NB + b], og * tanhf(c),
                           __ATOMIC_RELAXED, __HIP_MEMORY_SCOPE_AGENT);
      }
    }
    if (s < NT) grid_barrier<NPOLL>(flags, wg, (unsigned int)(s + 1), tid, gaveup);
  }
}

__global__ __launch_bounds__(256, 1) void k3_recurrence(float* ws,
    const float* Whh0, const float* Wih0, const float* bih0, const float* bhh0,
    const float* Wih1, const float* Whh1, const float* bih1, const float* bhh1) {
  extern __shared__ float smem[];
  const int wg = blockIdx.x, tid = threadIdx.x;
  if (wg < 128) lstm_loop<24, 256, 0>(ws, smem, Whh0, Wih0, bih0, bhh0, (wg)*4, tid, wg);
  else          lstm_loop<32, 512, 1>(ws, smem, Wih1, Whh1, bih1, bhh1, (wg-128)*4, tid, wg);
}

// ---------------- K4: ctx[l][b][d] = h1[t] @ Wp + bp ----------------
// grid 244 (= t), 256 threads (= d); h1[t] tile staged in LDS
__global__ __launch_bounds__(256) void k4_proj(float* __restrict__ ws,
                                               const float* __restrict__ Wp,
                                               const float* __restrict__ bp) {
  const int t = blockIdx.x, tid = threadIdx.x;
  extern __shared__ float sh[];  // h1[t][k][b]: 512*32 floats
  const float* hsrc = ws + H1_OFF + (size_t)(t+1)*NH*NB;
  for (int i = 0; i < 64; ++i) sh[i*256 + tid] = hsrc[i*256 + tid];  // coalesced
  __syncthreads();
  const int d = tid;
  const float bpd = bp[d];
  float4 acc[8];
#pragma unroll
  for (int q = 0; q < 8; ++q) { acc[q].x = bpd; acc[q].y = bpd; acc[q].z = bpd; acc[q].w = bpd; }
  for (int k = 0; k < NH; ++k) {
    const float w = Wp[(size_t)k*ND + d];       // coalesced
    const float4* hr = (const float4*)(sh + (size_t)k*NB);
#pragma unroll
    for (int q = 0; q < 8; ++q) {
      float4 h = hr[q];                          // broadcast read
      acc[q].x += h.x*w; acc[q].y += h.y*w; acc[q].z += h.z*w; acc[q].w += h.w*w;
    }
  }
#pragma unroll
  for (int q = 0; q < 8; ++q) {
    ws[CTX_OFF + ((size_t)t*NB + q*4 + 0)*ND + d] = acc[q].x;
    ws[CTX_OFF + ((size_t)t*NB + q*4 + 1)*ND + d] = acc[q].y;
    ws[CTX_OFF + ((size_t)t*NB + q*4 + 2)*ND + d] = acc[q].z;
    ws[CTX_OFF + ((size_t)t*NB + q*4 + 3)*ND + d] = acc[q].w;
  }
}

// ---------------- K5: 65 dot-products + logsumexp -> ce[l,b] ----------------
// grid 7808 = (l,b), 256 threads = 4 waves; each wave handles preds n = wv, wv+4, ...
__global__ __launch_bounds__(256) void k5_scores(float* __restrict__ ws,
                                                 const int* __restrict__ idxs) {
  const int blk = blockIdx.x;
  const int l = blk >> 5, b = blk & 31;
  const int tid = threadIdx.x, lane = tid & 63, wv = tid >> 6;
  const float* ctx = ws + CTX_OFF + ((size_t)l*NB + b)*ND;
  const float4 c4 = ((const float4*)ctx)[lane];
  __shared__ float preds[66];
  for (int n = wv; n < 65; n += 4) {
    const float* rowp;
    if (n == 0) {
      rowp = ws + ENC_OFF + ((size_t)(b*NT + NSP + l))*ND;
    } else {
      int idx = idxs[(size_t)l*(NB*NNF) + b*NNF + (n-1)];
      int sq = idx % (NT-1);
      int bb = idx / (NT-1);
      sq += (sq >= l + NSP) ? 1 : 0;
      rowp = ws + ENC_OFF + ((size_t)(bb*NT + sq))*ND;
    }
    float4 r4 = ((const float4*)rowp)[lane];
    float p = c4.x*r4.x + c4.y*r4.y + c4.z*r4.z + c4.w*r4.w;
#pragma unroll
    for (int m = 1; m < 64; m <<= 1) p += __shfl_xor(p, m, 64);
    if (lane == 0) preds[n] = p;
  }
  __syncthreads();
  if (wv == 0) {
    float p = preds[lane];
    float p64 = preds[64], p0 = preds[0];
    float mx = p;
#pragma unroll
    for (int m = 1; m < 64; m <<= 1) mx = fmaxf(mx, __shfl_xor(mx, m, 64));
    mx = fmaxf(mx, p64);
    float e = expf(p - mx);
#pragma unroll
    for (int m = 1; m < 64; m <<= 1) e += __shfl_xor(e, m, 64);
    e += expf(p64 - mx);
    if (lane == 0) ws[CE_OFF + (size_t)l*NB + b] = mx + logf(e) - p0;
  }
}

// ---------------- K6: loss = sum(ce) / 32 ----------------
__global__ __launch_bounds__(256) void k6_reduce(const float* __restrict__ ws,
                                                 float* __restrict__ out) {
  const int tid = threadIdx.x;
  float s = 0.0f;
  for (int i = tid; i < NL*NB; i += 256) s += ws[CE_OFF + i];
  __shared__ float red[256];
  red[tid] = s;
  __syncthreads();
  for (int off = 128; off > 0; off >>= 1) {
    if (tid < off) red[tid] += red[tid + off];
    __syncthreads();
  }
  if (tid == 0) out[0] = red[0] * (1.0f / 32.0f);
}

// ---------------- launcher ----------------
extern "C" void kernel_launch(void* const* d_in, const int* in_sizes, int n_in,
                              void* d_out, int out_size, void* d_ws, size_t ws_size,
                              hipStream_t stream) {
  const float* x     = (const float*)d_in[0];
  const float* W_enc = (const float*)d_in[1];
  const float* b_enc = (const float*)d_in[2];
  const float* Wih0  = (const float*)d_in[3];
  const float* Whh0  = (const float*)d_in[4];
  const float* bih0  = (const float*)d_in[5];
  const float* bhh0  = (const float*)d_in[6];
  const float* Wih1  = (const float*)d_in[7];
  const float* Whh1  = (const float*)d_in[8];
  const float* bih1  = (const float*)d_in[9];
  const float* bhh1  = (const float*)d_in[10];
  const float* Wp    = (const float*)d_in[11];
  const float* bp    = (const float*)d_in[12];
  const int*   idxs  = (const int*)d_in[13];
  float* ws  = (float*)d_ws;
  float* out = (float*)d_out;

  (void)in_sizes; (void)n_in; (void)out_size; (void)ws_size;

  hipFuncSetAttribute((const void*)k3_recurrence,
                      hipFuncAttributeMaxDynamicSharedMemorySize, K3_SMEM_BYTES);
  hipFuncSetAttribute((const void*)k4_proj,
                      hipFuncAttributeMaxDynamicSharedMemorySize, 65536);

  k1_encoder  <<<128,  256, 0, stream>>>(ws, x, W_enc, b_enc);
  k2_transpose<<<1024, 256, 0, stream>>>(ws);

  // K3: cooperative launch guarantees co-residency of all 256 wgs (1/CU).
  {
    float* ws_ = ws;
    const float *a0 = Whh0, *a1 = Wih0, *a2 = bih0, *a3 = bhh0;
    const float *a4 = Wih1, *a5 = Whh1, *a6 = bih1, *a7 = bhh1;
    void* params[] = {(void*)&ws_, (void*)&a0, (void*)&a1, (void*)&a2, (void*)&a3,
                      (void*)&a4, (void*)&a5, (void*)&a6, (void*)&a7};
    hipError_t err = hipLaunchCooperativeKernel((const void*)k3_recurrence,
                                                dim3(NWG), dim3(256), params,
                                                K3_SMEM_BYTES, stream);
    if (err != hipSuccess) {
      k3_recurrence<<<NWG, 256, K3_SMEM_BYTES, stream>>>(ws, Whh0, Wih0, bih0, bhh0,
                                                         Wih1, Whh1, bih1, bhh1);
    }
  }

  k4_proj     <<<NL,   256, 65536, stream>>>(ws, Wp, bp);
  k5_scores   <<<NL*NB,256, 0, stream>>>(ws, idxs);
  k6_reduce   <<<1,    256, 0, stream>>>(ws, out);
}

// Round 6
// 4364.429 us; speedup vs baseline: 1.6609x; 1.4566x over previous
//
#include <hip/hip_runtime.h>
#include <cstdint>

#define DEV_INLINE __device__ __forceinline__

typedef float  f32x4 __attribute__((ext_vector_type(4)));

constexpr int NB = 32;    // batch
constexpr int NC = 128;   // channels
constexpr int NT = 256;   // seq len
constexpr int ND = 256;   // enc dim
constexpr int NH = 512;   // hidden
constexpr int NSP = 12;
constexpr int NL = NT - NSP;  // 244
constexpr int NNF = 64;
constexpr int NWG = 256;  // recurrence workgroups (1 per CU)

// ---- workspace layout (fp32 words) ----
constexpr size_t ENC_OFF   = 0;                                  // enc[b][t][d]
constexpr size_t ENCT_OFF  = ENC_OFF  + (size_t)NB*NT*ND;        // encT[t][d][b]
constexpr size_t H0_OFF    = ENCT_OFF + (size_t)NT*ND*NB;        // h0 slabs t=-1..255 -> 257 x [k][b]
constexpr size_t H1_OFF    = H0_OFF   + (size_t)(NT+1)*NH*NB;
constexpr size_t CTX_OFF   = H1_OFF   + (size_t)(NT+1)*NH*NB;    // ctx[l][b][d]
constexpr size_t CE_OFF    = CTX_OFF  + (size_t)NL*NB*ND;        // ce[l*32+b]
constexpr size_t FLAGS_OFF = CE_OFF   + (size_t)NL*NB;           // 256 uint flags

// K3 dynamic LDS: A region (max 1024*36+128 words) + redbuf (2304) + cstate (128)
constexpr int K3_SMEM_BYTES = (1024*36 + 128 + 2304 + 128) * 4;  // 157,696 B

DEV_INLINE float sigm(float x) { return 1.0f / (1.0f + expf(-x)); }

// ---------------- K1: encoder GEMM + zero-init of flags / h[-1] slabs ----------------
// grid 128 = (b, t-tile of 64), 256 threads
__global__ __launch_bounds__(256) void k1_encoder(float* __restrict__ ws,
                                                  const float* __restrict__ x,
                                                  const float* __restrict__ W_enc,
                                                  const float* __restrict__ b_enc) {
  const int blk = blockIdx.x, tid = threadIdx.x;
  // zero duty: flags (block 0) + h0/h1 slab -1 (128 floats each per block)
  if (blk == 0) ((unsigned int*)(ws + FLAGS_OFF))[tid] = 0u;
  if (tid < 128) ws[H0_OFF + (size_t)blk*128 + tid] = 0.0f;
  else           ws[H1_OFF + (size_t)blk*128 + (tid-128)] = 0.0f;

  const int b = blk >> 2;
  const int t0 = (blk & 3) * 64;
  __shared__ float xs[NC][64];
  const int lane = tid & 63, wq = tid >> 6;
  for (int c = wq; c < NC; c += 4)
    xs[c][lane] = x[((size_t)(b*NC + c))*NT + t0 + lane];   // coalesced along t
  __syncthreads();

  const int d = tid;
  const float be = b_enc[d];
  float4 acc[16];
#pragma unroll
  for (int q = 0; q < 16; ++q) { acc[q].x = be; acc[q].y = be; acc[q].z = be; acc[q].w = be; }
  for (int c = 0; c < NC; ++c) {
    const float w = W_enc[(size_t)c*ND + d];     // coalesced, L2-hot
    const float4* xr = (const float4*)(&xs[c][0]);
#pragma unroll
    for (int q = 0; q < 16; ++q) {
      float4 xv = xr[q];
      acc[q].x += xv.x*w; acc[q].y += xv.y*w; acc[q].z += xv.z*w; acc[q].w += xv.w*w;
    }
  }
#pragma unroll
  for (int q = 0; q < 16; ++q) {
    ws[ENC_OFF + ((size_t)(b*NT + t0 + q*4 + 0))*ND + d] = acc[q].x;
    ws[ENC_OFF + ((size_t)(b*NT + t0 + q*4 + 1))*ND + d] = acc[q].y;
    ws[ENC_OFF + ((size_t)(b*NT + t0 + q*4 + 2))*ND + d] = acc[q].z;
    ws[ENC_OFF + ((size_t)(b*NT + t0 + q*4 + 3))*ND + d] = acc[q].w;
  }
}

// ---------------- K2: transpose enc[b][t][d] -> encT[t][d][b] ----------------
// grid 1024 = (t, d-quad of 64), 256 threads
__global__ __launch_bounds__(256) void k2_transpose(float* __restrict__ ws) {
  const int t = blockIdx.x >> 2;
  const int d0 = (blockIdx.x & 3) * 64;
  const int tid = threadIdx.x;
  __shared__ float tile[NB][65];  // +1 pad: write-phase reads stride-65 -> conflict-free
  const int lane = tid & 63, wq = tid >> 6;
  for (int b = wq; b < NB; b += 4)
    tile[b][lane] = ws[ENC_OFF + ((size_t)(b*NT + t))*ND + d0 + lane];  // coalesced
  __syncthreads();
#pragma unroll
  for (int i = 0; i < 8; ++i) {
    int idx = i*256 + tid;
    int dd = idx >> 5, b = idx & 31;
    ws[ENCT_OFF + ((size_t)(t*ND + d0 + dd))*NB + b] = tile[b][dd];     // coalesced
  }
}

// ---------------- grid barrier: write-through flags, NO L2 maintenance ----------------
// Protocol proven correct in r5 (absmax 0.0): producers store h via agent-scope
// relaxed atomics; __syncthreads drains vmcnt; flag store agent-relaxed; consumers
// poll agent-relaxed and read h via agent-relaxed atomic loads. No wbl2/inv.
// Timeout: give up after ~131K polls -> diagnosable wrong result, not a wedged GPU.
template<int NPOLL>
DEV_INLINE void grid_barrier(unsigned int* flags, int wg, unsigned int target, int tid,
                             bool& gaveup) {
  __syncthreads();  // vmcnt(0): this wg's write-through h-stores have reached LLC
  if (tid == 0)
    __hip_atomic_store(&flags[wg], target, __ATOMIC_RELAXED, __HIP_MEMORY_SCOPE_AGENT);
  if (tid < 64 && !gaveup) {
    int iters = 0;
    for (;;) {
      bool ok = true;
#pragma unroll
      for (int i = 0; i < NPOLL/64; ++i) {
        unsigned int v = __hip_atomic_load(&flags[tid + i*64], __ATOMIC_RELAXED, __HIP_MEMORY_SCOPE_AGENT);
        ok = ok && (v >= target);
      }
      if (__all(ok)) break;
      if (++iters > (1 << 17)) { gaveup = true; break; }
      __builtin_amdgcn_s_sleep(2);
    }
  }
  __syncthreads();
}

// ---------------- K3: persistent pipelined 2-layer LSTM recurrence ----------------
// 256 wgs x 256 threads, 1 wg/CU (LDS-capped -> 1 wave/SIMD, full 512-VGPR budget).
// wg<128: layer0, else layer1. Per wg: 16 gate-rows (4 units x 4 gates), weights in
// VGPRs (2 rows x KC per thread), A=[k][b] staged in LDS with per-chunk +4-word pad
// (8 ks-groups/wave -> 8 distinct bank-quads -> conflict-free broadcast b128 reads).
// Staging is COALESCED: consecutive lanes load consecutive 8B granules of each slab
// (wave instr = 512B contiguous = 8 full lines), then scatter to padded LDS rows.
template<int KC, int WBS, int LAYER>
DEV_INLINE void lstm_loop(float* __restrict__ ws, float* __restrict__ smem,
                          const float* __restrict__ Wa, const float* __restrict__ Wb,
                          const float* __restrict__ bih, const float* __restrict__ bhh,
                          int u0, int tid, int wg) {
  constexpr int KTOT = KC * 32;            // 768 (L0) or 1024 (L1)
  constexpr int NSLAB = (LAYER == 0) ? 1 : 2;   // h slabs staged (64KB each)
  constexpr int AW   = KTOT*36 + 128;      // A region words
  constexpr int NPOLL = (LAYER == 0) ? 128 : 256;
  float* redbuf = smem + AW;               // [4][16][36]
  float* cst    = redbuf + 2304;           // c-state [128]
  unsigned int* flags = (unsigned int*)(ws + FLAGS_OFF);

  const int rg = tid & 7, ks = tid >> 3;
  bool gaveup = false;

  // --- persistent weight registers: 2 rows x KC (float4 preload) ---
  int row[2];
#pragma unroll
  for (int j = 0; j < 2; ++j) {
    int ridx = rg*2 + j;                   // gate = ridx&3, unit-lane = ridx>>2
    row[j] = (ridx & 3)*NH + u0 + (ridx >> 2);
  }
  float wreg[2][KC];
#pragma unroll
  for (int k0 = 0; k0 < KC/4; ++k0) {
    const int kk = ks*KC + k0*4;           // 16B-aligned; NH boundary is float4-aligned
#pragma unroll
    for (int j = 0; j < 2; ++j) {
      const float4 w4 = (kk < NH)
        ? *(const float4*)&Wa[(size_t)row[j]*NH + kk]
        : *(const float4*)&Wb[(size_t)row[j]*WBS + (kk - NH)];
      wreg[j][k0*4+0] = w4.x; wreg[j][k0*4+1] = w4.y;
      wreg[j][k0*4+2] = w4.z; wreg[j][k0*4+3] = w4.w;
    }
  }
  // --- finalize-thread constants + c-state init ---
  float bsum[4] = {0,0,0,0};
  if (tid < 128) {
    int ul = tid >> 5;
#pragma unroll
    for (int g = 0; g < 4; ++g)
      bsum[g] = bih[g*NH + u0 + ul] + bhh[g*NH + u0 + ul];
    cst[tid] = 0.0f;
  }
  __syncthreads();

  const float* Aread = smem + (size_t)ks * (KC*36 + 4);

  for (int s = 0; s <= NT; ++s) {
    const int t = (LAYER == 0) ? s : s - 1;
    const bool active = (LAYER == 0) ? (s < NT) : (s >= 1);
    if (active) {
      const float* srcA = (LAYER == 0) ? ws + H0_OFF + (size_t)t*NH*NB        // h0[t-1]
                                       : ws + H0_OFF + (size_t)(t+1)*NH*NB;   // h0[t]
      const float* srcB = (LAYER == 0) ? ws + ENCT_OFF + (size_t)t*ND*NB      // enc_t[d][b]
                                       : ws + H1_OFF + (size_t)t*NH*NB;       // h1[t-1]
      float* hout = ((LAYER == 0) ? ws + H0_OFF : ws + H1_OFF) + (size_t)(t+1)*NH*NB;

      // --- COALESCED stage into LDS.
      //     h slabs (64KB each): 32 x 8B agent-atomic loads/thread, lane-contiguous.
      //       dblIdx = j*256+tid -> row k = dblIdx>>4, col b0 = (dblIdx&15)*2.
      //     encT (L0, 32KB): 8 x 16B plain loads/thread, lane-contiguous.
      //     All issues before all LDS writes (sched_barrier fence).
      //     LDS word addr = k*36 + (k/KC)*4 + b0 ---
      {
        double vh[NSLAB][32];
        f32x4 ve[8];
#pragma unroll
        for (int i = 0; i < NSLAB; ++i) {
          const double* src = (const double*)((i == 0) ? srcA : srcB);
#pragma unroll
          for (int j = 0; j < 32; ++j)
            vh[i][j] = __hip_atomic_load(src + j*256 + tid, __ATOMIC_RELAXED, __HIP_MEMORY_SCOPE_AGENT);
        }
        if (LAYER == 0) {
#pragma unroll
          for (int j = 0; j < 8; ++j)
            ve[j] = ((const f32x4*)srcB)[j*256 + tid];
        }
        __builtin_amdgcn_sched_barrier(0);   // keep all issues above all LDS writes
#pragma unroll
        for (int i = 0; i < NSLAB; ++i) {
#pragma unroll
          for (int j = 0; j < 32; ++j) {
            const int dblIdx = j*256 + tid;
            const int k = (i*512) + (dblIdx >> 4);
            const int b0 = (dblIdx & 15)*2;
            *(double*)(smem + (size_t)k*36 + (k/KC)*4 + b0) = vh[i][j];  // ds_write_b64
          }
        }
        if (LAYER == 0) {
#pragma unroll
          for (int j = 0; j < 8; ++j) {
            const int f4Idx = j*256 + tid;
            const int k = 512 + (f4Idx >> 3);
            const int b0 = (f4Idx & 7)*4;
            *(f32x4*)(smem + (size_t)k*36 + (k/KC)*4 + b0) = ve[j];      // ds_write_b128
          }
        }
      }
      __syncthreads();

      // --- FMA: partial dots over this thread's K-chunk, 2 rows x 32 batches ---
      float4 acc[2][8];
#pragma unroll
      for (int j = 0; j < 2; ++j)
#pragma unroll
        for (int m = 0; m < 8; ++m) { acc[j][m].x = 0; acc[j][m].y = 0; acc[j][m].z = 0; acc[j][m].w = 0; }
#pragma unroll
      for (int k = 0; k < KC; ++k) {
        const float4* ar = (const float4*)(Aread + (size_t)k*36);
        const float w0 = wreg[0][k], w1 = wreg[1][k];
#pragma unroll
        for (int m = 0; m < 8; ++m) {
          float4 a = ar[m];
          acc[0][m].x += a.x*w0; acc[0][m].y += a.y*w0; acc[0][m].z += a.z*w0; acc[0][m].w += a.w*w0;
          acc[1][m].x += a.x*w1; acc[1][m].y += a.y*w1; acc[1][m].z += a.z*w1; acc[1][m].w += a.w*w1;
        }
      }

      // --- intra-wave reduce over ks (tid bits 3..5) ---
#pragma unroll
      for (int mask = 8; mask <= 32; mask <<= 1) {
#pragma unroll
        for (int j = 0; j < 2; ++j)
#pragma unroll
          for (int m = 0; m < 8; ++m) {
            acc[j][m].x += __shfl_xor(acc[j][m].x, mask, 64);
            acc[j][m].y += __shfl_xor(acc[j][m].y, mask, 64);
            acc[j][m].z += __shfl_xor(acc[j][m].z, mask, 64);
            acc[j][m].w += __shfl_xor(acc[j][m].w, mask, 64);
          }
      }
      if ((tid & 56) == 0) {          // one lane-group per wave writes wave-partials
        int wv = tid >> 6;
#pragma unroll
        for (int j = 0; j < 2; ++j)
#pragma unroll
          for (int m = 0; m < 8; ++m)
            *((float4*)(redbuf + (size_t)(wv*16 + rg*2 + j)*36 + 4*m)) = acc[j][m];
      }
      __syncthreads();

      // --- finalize: sum 4 wave-partials + bias, LSTM cell update, write h ---
      if (tid < 128) {
        int ul = tid >> 5, b = tid & 31;
        float gv[4];
#pragma unroll
        for (int g = 0; g < 4; ++g) {
          float ssum = bsum[g];
#pragma unroll
          for (int wv = 0; wv < 4; ++wv)
            ssum += redbuf[(size_t)(wv*16 + ul*4 + g)*36 + b];
          gv[g] = ssum;
        }
        float ig = sigm(gv[0]);
        float fg = sigm(gv[1]);
        float gg = tanhf(gv[2]);
        float og = sigm(gv[3]);
        float c = fg * cst[tid] + ig * gg;
        cst[tid] = c;
        // write-through store: never dirty in L2, at LLC after vmcnt drain
        __hip_atomic_store(&hout[(size_t)(u0 + ul)*NB + b], og * tanhf(c),
                           __ATOMIC_RELAXED, __HIP_MEMORY_SCOPE_AGENT);
      }
    }
    if (s < NT) grid_barrier<NPOLL>(flags, wg, (unsigned int)(s + 1), tid, gaveup);
  }
}

__global__ __launch_bounds__(256, 1) void k3_recurrence(float* ws,
    const float* Whh0, const float* Wih0, const float* bih0, const float* bhh0,
    const float* Wih1, const float* Whh1, const float* bih1, const float* bhh1) {
  extern __shared__ float smem[];
  const int wg = blockIdx.x, tid = threadIdx.x;
  if (wg < 128) lstm_loop<24, 256, 0>(ws, smem, Whh0, Wih0, bih0, bhh0, (wg)*4, tid, wg);
  else          lstm_loop<32, 512, 1>(ws, smem, Wih1, Whh1, bih1, bhh1, (wg-128)*4, tid, wg);
}

// ---------------- K4: ctx[l][b][d] = h1[t] @ Wp + bp ----------------
// grid 244 (= t), 256 threads (= d); h1[t] tile staged in LDS
__global__ __launch_bounds__(256) void k4_proj(float* __restrict__ ws,
                                               const float* __restrict__ Wp,
                                               const float* __restrict__ bp) {
  const int t = blockIdx.x, tid = threadIdx.x;
  extern __shared__ float sh[];  // h1[t][k][b]: 512*32 floats
  const float* hsrc = ws + H1_OFF + (size_t)(t+1)*NH*NB;
  for (int i = 0; i < 64; ++i) sh[i*256 + tid] = hsrc[i*256 + tid];  // coalesced
  __syncthreads();
  const int d = tid;
  const float bpd = bp[d];
  float4 acc[8];
#pragma unroll
  for (int q = 0; q < 8; ++q) { acc[q].x = bpd; acc[q].y = bpd; acc[q].z = bpd; acc[q].w = bpd; }
  for (int k = 0; k < NH; ++k) {
    const float w = Wp[(size_t)k*ND + d];       // coalesced
    const float4* hr = (const float4*)(sh + (size_t)k*NB);
#pragma unroll
    for (int q = 0; q < 8; ++q) {
      float4 h = hr[q];                          // broadcast read
      acc[q].x += h.x*w; acc[q].y += h.y*w; acc[q].z += h.z*w; acc[q].w += h.w*w;
    }
  }
#pragma unroll
  for (int q = 0; q < 8; ++q) {
    ws[CTX_OFF + ((size_t)t*NB + q*4 + 0)*ND + d] = acc[q].x;
    ws[CTX_OFF + ((size_t)t*NB + q*4 + 1)*ND + d] = acc[q].y;
    ws[CTX_OFF + ((size_t)t*NB + q*4 + 2)*ND + d] = acc[q].z;
    ws[CTX_OFF + ((size_t)t*NB + q*4 + 3)*ND + d] = acc[q].w;
  }
}

// ---------------- K5: 65 dot-products + logsumexp -> ce[l,b] ----------------
// grid 7808 = (l,b), 256 threads = 4 waves; each wave handles preds n = wv, wv+4, ...
__global__ __launch_bounds__(256) void k5_scores(float* __restrict__ ws,
                                                 const int* __restrict__ idxs) {
  const int blk = blockIdx.x;
  const int l = blk >> 5, b = blk & 31;
  const int tid = threadIdx.x, lane = tid & 63, wv = tid >> 6;
  const float* ctx = ws + CTX_OFF + ((size_t)l*NB + b)*ND;
  const float4 c4 = ((const float4*)ctx)[lane];
  __shared__ float preds[66];
  for (int n = wv; n < 65; n += 4) {
    const float* rowp;
    if (n == 0) {
      rowp = ws + ENC_OFF + ((size_t)(b*NT + NSP + l))*ND;
    } else {
      int idx = idxs[(size_t)l*(NB*NNF) + b*NNF + (n-1)];
      int sq = idx % (NT-1);
      int bb = idx / (NT-1);
      sq += (sq >= l + NSP) ? 1 : 0;
      rowp = ws + ENC_OFF + ((size_t)(bb*NT + sq))*ND;
    }
    float4 r4 = ((const float4*)rowp)[lane];
    float p = c4.x*r4.x + c4.y*r4.y + c4.z*r4.z + c4.w*r4.w;
#pragma unroll
    for (int m = 1; m < 64; m <<= 1) p += __shfl_xor(p, m, 64);
    if (lane == 0) preds[n] = p;
  }
  __syncthreads();
  if (wv == 0) {
    float p = preds[lane];
    float p64 = preds[64], p0 = preds[0];
    float mx = p;
#pragma unroll
    for (int m = 1; m < 64; m <<= 1) mx = fmaxf(mx, __shfl_xor(mx, m, 64));
    mx = fmaxf(mx, p64);
    float e = expf(p - mx);
#pragma unroll
    for (int m = 1; m < 64; m <<= 1) e += __shfl_xor(e, m, 64);
    e += expf(p64 - mx);
    if (lane == 0) ws[CE_OFF + (size_t)l*NB + b] = mx + logf(e) - p0;
  }
}

// ---------------- K6: loss = sum(ce) / 32 ----------------
__global__ __launch_bounds__(256) void k6_reduce(const float* __restrict__ ws,
                                                 float* __restrict__ out) {
  const int tid = threadIdx.x;
  float s = 0.0f;
  for (int i = tid; i < NL*NB; i += 256) s += ws[CE_OFF + i];
  __shared__ float red[256];
  red[tid] = s;
  __syncthreads();
  for (int off = 128; off > 0; off >>= 1) {
    if (tid < off) red[tid] += red[tid + off];
    __syncthreads();
  }
  if (tid == 0) out[0] = red[0] * (1.0f / 32.0f);
}

// ---------------- launcher ----------------
extern "C" void kernel_launch(void* const* d_in, const int* in_sizes, int n_in,
                              void* d_out, int out_size, void* d_ws, size_t ws_size,
                              hipStream_t stream) {
  const float* x     = (const float*)d_in[0];
  const float* W_enc = (const float*)d_in[1];
  const float* b_enc = (const float*)d_in[2];
  const float* Wih0  = (const float*)d_in[3];
  const float* Whh0  = (const float*)d_in[4];
  const float* bih0  = (const float*)d_in[5];
  const float* bhh0  = (const float*)d_in[6];
  const float* Wih1  = (const float*)d_in[7];
  const float* Whh1  = (const float*)d_in[8];
  const float* bih1  = (const float*)d_in[9];
  const float* bhh1  = (const float*)d_in[10];
  const float* Wp    = (const float*)d_in[11];
  const float* bp    = (const float*)d_in[12];
  const int*   idxs  = (const int*)d_in[13];
  float* ws  = (float*)d_ws;
  float* out = (float*)d_out;

  (void)in_sizes; (void)n_in; (void)out_size; (void)ws_size;

  hipFuncSetAttribute((const void*)k3_recurrence,
                      hipFuncAttributeMaxDynamicSharedMemorySize, K3_SMEM_BYTES);
  hipFuncSetAttribute((const void*)k4_proj,
                      hipFuncAttributeMaxDynamicSharedMemorySize, 65536);

  k1_encoder  <<<128,  256, 0, stream>>>(ws, x, W_enc, b_enc);
  k2_transpose<<<1024, 256, 0, stream>>>(ws);

  // K3: cooperative launch guarantees co-residency of all 256 wgs (1/CU).
  {
    float* ws_ = ws;
    const float *a0 = Whh0, *a1 = Wih0, *a2 = bih0, *a3 = bhh0;
    const float *a4 = Wih1, *a5 = Whh1, *a6 = bih1, *a7 = bhh1;
    void* params[] = {(void*)&ws_, (void*)&a0, (void*)&a1, (void*)&a2, (void*)&a3,
                      (void*)&a4, (void*)&a5, (void*)&a6, (void*)&a7};
    hipError_t err = hipLaunchCooperativeKernel((const void*)k3_recurrence,
                                                dim3(NWG), dim3(256), params,
                                                K3_SMEM_BYTES, stream);
    if (err != hipSuccess) {
      k3_recurrence<<<NWG, 256, K3_SMEM_BYTES, stream>>>(ws, Whh0, Wih0, bih0, bhh0,
                                                         Wih1, Whh1, bih1, bhh1);
    }
  }

  k4_proj     <<<NL,   256, 65536, stream>>>(ws, Wp, bp);
  k5_scores   <<<NL*NB,256, 0, stream>>>(ws, idxs);
  k6_reduce   <<<1,    256, 0, stream>>>(ws, out);
}